// Round 1
// baseline (13479.550 us; speedup 1.0000x reference)
//
#include <hip/hip_runtime.h>
#include <hip/hip_bf16.h>

// Problem constants (match the reference)
constexpr int B = 4;
constexpr int N = 16384;
constexpr int S = 4096;       // N * 0.25
constexpr int K = 32;
constexpr float BIG = 1e30f;

// Output layout (flat f32, concatenated in reference return order)
constexpr size_t OFF_COORD = 0;                       // node_coord_dst [B*S*3]
constexpr size_t OFF_ESRC  = (size_t)B * S * 3;       // 49152, edge_src [B*S*K]
constexpr size_t OFF_EDST  = OFF_ESRC + (size_t)B * S * K;   // 573440
constexpr size_t OFF_MASK  = OFF_EDST + (size_t)B * S * K;   // 1097728
constexpr size_t OFF_DEG   = OFF_MASK + (size_t)B * S * K;   // 1622016
constexpr size_t OFF_BATCH = OFF_DEG + (size_t)B * S;        // 1638400
constexpr size_t OFF_NIDX  = OFF_BATCH + (size_t)B * S;      // 1654784

#define NT_FPS 1024
#define PPT (N / NT_FPS)       // 16 points per thread
#define NWAVE (NT_FPS / 64)    // 16 waves

// ---------------- Kernel 1: farthest point sampling (one block per cloud) ---
__global__ __launch_bounds__(NT_FPS)
void fps_kernel(const float* __restrict__ pts, int* __restrict__ seq) {
    const int b = blockIdx.x;
    const float* p = pts + (size_t)b * N * 3;
    const int t = threadIdx.x;
    const int lane = t & 63;
    const int wave = t >> 6;

    float px[PPT], py[PPT], pz[PPT], dd[PPT];
    const int base = t * PPT;
#pragma unroll
    for (int j = 0; j < PPT; ++j) {
        px[j] = p[(base + j) * 3 + 0];
        py[j] = p[(base + j) * 3 + 1];
        pz[j] = p[(base + j) * 3 + 2];
        dd[j] = BIG;
    }

    __shared__ float s_lx, s_ly, s_lz;
    __shared__ float s_pv[NWAVE];
    __shared__ int   s_pi[NWAVE];

    if (t == 0) {
        seq[b * S + 0] = 0;          // first sample is index 0 (random_start=False)
        s_lx = px[0]; s_ly = py[0]; s_lz = pz[0];
    }
    __syncthreads();

    for (int step = 1; step < S; ++step) {
        const float lx = s_lx, ly = s_ly, lz = s_lz;
        float bv = -1.0f;
        int   bi = 0x7fffffff;
#pragma unroll
        for (int j = 0; j < PPT; ++j) {
            // Exact f32 arithmetic, no FMA contraction: ((dx*dx + dy*dy) + dz*dz)
            float dx = __fsub_rn(px[j], lx);
            float dy = __fsub_rn(py[j], ly);
            float dz = __fsub_rn(pz[j], lz);
            float d  = __fadd_rn(__fadd_rn(__fmul_rn(dx, dx), __fmul_rn(dy, dy)),
                                 __fmul_rn(dz, dz));
            float nd = fminf(dd[j], d);
            dd[j] = nd;
            if (nd > bv) { bv = nd; bi = base + j; }   // strict > keeps lowest index
        }
        // wave-level argmax (lowest index wins ties)
#pragma unroll
        for (int off = 32; off >= 1; off >>= 1) {
            float ov = __shfl_down(bv, off);
            int   oi = __shfl_down(bi, off);
            if (ov > bv || (ov == bv && oi < bi)) { bv = ov; bi = oi; }
        }
        if (lane == 0) { s_pv[wave] = bv; s_pi[wave] = bi; }
        __syncthreads();

        // every thread redundantly reduces the 16 wave partials (identical result)
        float wv = s_pv[0];
        int   wi = s_pi[0];
#pragma unroll
        for (int q = 1; q < NWAVE; ++q) {
            float v = s_pv[q]; int i2 = s_pi[q];
            if (v > wv || (v == wv && i2 < wi)) { wv = v; wi = i2; }
        }
        // the owning thread publishes the winner's coordinates
        if (t == (wi >> 4)) {            // wi / PPT
            int j = wi & (PPT - 1);
            s_lx = px[j]; s_ly = py[j]; s_lz = pz[j];
            seq[b * S + step] = wi;
        }
        __syncthreads();
    }
}

// ---------------- Kernel 2: sort FPS indices (bitmap rank), gather dst ------
#define NT_SORT 512
__global__ __launch_bounds__(NT_SORT)
void sort_gather_kernel(const float* __restrict__ pts, const int* __restrict__ seq,
                        int* __restrict__ sorted, float* __restrict__ out) {
    const int b = blockIdx.x;
    const int t = threadIdx.x;
    __shared__ unsigned int bm[N / 32];   // 512 words
    __shared__ int pfx[N / 32];           // inclusive popcount prefix
    __shared__ int s_sorted[S];

    for (int i = t; i < N / 32; i += NT_SORT) bm[i] = 0u;
    __syncthreads();
    for (int i = t; i < S; i += NT_SORT) {
        int v = seq[b * S + i];
        atomicOr(&bm[v >> 5], 1u << (v & 31));
    }
    __syncthreads();

    // Hillis-Steele inclusive scan over 512 word popcounts (NT_SORT == 512)
    int myc = __popc(bm[t]);
    pfx[t] = myc;
    __syncthreads();
    for (int off = 1; off < N / 32; off <<= 1) {
        int v = (t >= off) ? pfx[t - off] : 0;
        __syncthreads();
        pfx[t] += v;
        __syncthreads();
    }

    // rank each selected index = #selected indices below it
    for (int i = t; i < S; i += NT_SORT) {
        int v = seq[b * S + i];
        int w = v >> 5;
        int rank = pfx[w] - __popc(bm[w]) + __popc(bm[w] & ((1u << (v & 31)) - 1u));
        s_sorted[rank] = v;
    }
    __syncthreads();

    for (int r = t; r < S; r += NT_SORT) {
        int v = s_sorted[r];
        int g = b * S + r;
        sorted[g] = v;
        out[OFF_COORD + 3 * (size_t)g + 0] = pts[((size_t)b * N + v) * 3 + 0];
        out[OFF_COORD + 3 * (size_t)g + 1] = pts[((size_t)b * N + v) * 3 + 1];
        out[OFF_COORD + 3 * (size_t)g + 2] = pts[((size_t)b * N + v) * 3 + 2];
        out[OFF_BATCH + g] = (float)b;
        out[OFF_NIDX + g]  = (float)(v + b * N);
    }
}

// ---------------- Kernel 3: radius ball query, one wave per dst point -------
#define CAP 512                 // in-radius candidate cap (mean ~35, P(>512)~0)
__global__ __launch_bounds__(256)
void ballq_kernel(const float* __restrict__ pts, const int* __restrict__ sorted,
                  float* __restrict__ out) {
    const int w    = threadIdx.x >> 6;
    const int lane = threadIdx.x & 63;
    const int g    = blockIdx.x * 4 + w;     // dst id, 0..B*S-1
    const int b    = g >> 12;                // / S
    const float R2 = (float)(0.08 * 0.08);   // JAX weak-scalar f32 demotion

    __shared__ float cd2[4][CAP];
    __shared__ int   cidx[4][CAP];
    __shared__ int   coor[4][K];

    const float Dx = out[OFF_COORD + 3 * (size_t)g + 0];
    const float Dy = out[OFF_COORD + 3 * (size_t)g + 1];
    const float Dz = out[OFF_COORD + 3 * (size_t)g + 2];
    const int self = sorted[g];

    const float* p = pts + (size_t)b * N * 3;
    const unsigned long long ltmask = (lane == 63) ? 0x7fffffffffffffffull
                                                   : ((1ull << lane) - 1ull);
    int cnt = 0, oor = 0;
    for (int i0 = 0; i0 < N; i0 += 64) {
        int i = i0 + lane;
        float dx = __fsub_rn(Dx, p[i * 3 + 0]);
        float dy = __fsub_rn(Dy, p[i * 3 + 1]);
        float dz = __fsub_rn(Dz, p[i * 3 + 2]);
        float d2 = __fadd_rn(__fadd_rn(__fmul_rn(dx, dx), __fmul_rn(dy, dy)),
                             __fmul_rn(dz, dz));
        bool in = (d2 <= R2);
        unsigned long long m = __ballot(in);
        if (in) {
            int pos = cnt + __popcll(m & ltmask);
            if (pos < CAP) { cd2[w][pos] = d2; cidx[w][pos] = i; }
        }
        if (oor < K) {  // collect first K out-of-radius indices (ascending)
            unsigned long long m2 = ~m;
            if (!in) {
                int p2 = oor + __popcll(m2 & ltmask);
                if (p2 < K) coor[w][p2] = i;
            }
            oor += __popcll(m2);
            if (oor > K) oor = K;
        }
        cnt += __popcll(m);
    }

    const int M  = cnt < CAP ? cnt : CAP;
    const int Mk = M < K ? M : K;
    const size_t eb = (size_t)g * K;
    int deg = 0;
    for (int c = lane; c < M; c += 64) {
        float myd = cd2[w][c];
        int   myi = cidx[w][c];
        int rank = 0;
        for (int j = 0; j < M; ++j) {
            float dj = cd2[w][j];
            int   ij = cidx[w][j];
            rank += (dj < myd || (dj == myd && ij < myi)) ? 1 : 0;
        }
        if (rank < K) {
            bool valid = (myi != self);
            out[OFF_ESRC + eb + rank] = (float)(myi + b * N);
            out[OFF_MASK + eb + rank] = valid ? 1.0f : 0.0f;
            deg += valid ? 1 : 0;
        }
    }
    for (int r = lane; r < K; r += 64) {
        out[OFF_EDST + eb + r] = (float)g;        // b*S + s == g
        if (r >= Mk) {                            // top_k pad: lowest-index OOR pts
            out[OFF_ESRC + eb + r] = (float)(coor[w][r - Mk] + b * N);
            out[OFF_MASK + eb + r] = 0.0f;
        }
    }
#pragma unroll
    for (int off = 32; off >= 1; off >>= 1) deg += __shfl_down(deg, off);
    if (lane == 0) out[OFF_DEG + g] = (float)deg;
}

extern "C" void kernel_launch(void* const* d_in, const int* in_sizes, int n_in,
                              void* d_out, int out_size, void* d_ws, size_t ws_size,
                              hipStream_t stream) {
    const float* pts = (const float*)d_in[0];
    float* out = (float*)d_out;
    int* seq    = (int*)d_ws;
    int* sorted = seq + (size_t)B * S;

    fps_kernel<<<B, NT_FPS, 0, stream>>>(pts, seq);
    sort_gather_kernel<<<B, NT_SORT, 0, stream>>>(pts, seq, sorted, out);
    ballq_kernel<<<(B * S) / 4, 256, 0, stream>>>(pts, sorted, out);
}

// Round 2
// 7041.646 us; speedup vs baseline: 1.9143x; 1.9143x over previous
//
#include <hip/hip_runtime.h>
#include <hip/hip_bf16.h>

// Problem constants (match the reference)
constexpr int B = 4;
constexpr int N = 16384;
constexpr int S = 4096;       // N * 0.25
constexpr int K = 32;
constexpr float BIG = 1e30f;

// Output layout (flat f32, concatenated in reference return order)
constexpr size_t OFF_COORD = 0;                       // node_coord_dst [B*S*3]
constexpr size_t OFF_ESRC  = (size_t)B * S * 3;       // edge_src [B*S*K]
constexpr size_t OFF_EDST  = OFF_ESRC + (size_t)B * S * K;
constexpr size_t OFF_MASK  = OFF_EDST + (size_t)B * S * K;
constexpr size_t OFF_DEG   = OFF_MASK + (size_t)B * S * K;
constexpr size_t OFF_BATCH = OFF_DEG + (size_t)B * S;
constexpr size_t OFF_NIDX  = OFF_BATCH + (size_t)B * S;

// ---------------- Kernel 1: farthest point sampling (one block per cloud) ---
// 512 threads x 32 points/thread; ALL per-point state in VGPRs (no dynamic
// indexing anywhere -> no scratch). One barrier per iteration; winner coords
// re-fetched via readfirstlane + scalar load instead of an LDS publish.
#define NT_FPS 512
#define PPT (N / NT_FPS)       // 32 points per thread
#define NWAVE (NT_FPS / 64)    // 8 waves

__global__ __launch_bounds__(NT_FPS)
void fps_kernel(const float* __restrict__ pts, int* __restrict__ seq) {
    const int b = blockIdx.x;
    const float* p = pts + (size_t)b * N * 3;
    const int t = threadIdx.x;
    const int lane = t & 63;
    const int wave = t >> 6;

    float px[PPT], py[PPT], pz[PPT], dd[PPT];
    const int base = t * PPT;
#pragma unroll
    for (int j = 0; j < PPT; ++j) {
        px[j] = p[(base + j) * 3 + 0];
        py[j] = p[(base + j) * 3 + 1];
        pz[j] = p[(base + j) * 3 + 2];
        dd[j] = BIG;
    }

    __shared__ unsigned long long s_part[2][NWAVE];   // parity double-buffer

    if (t == 0) seq[b * S + 0] = 0;       // first sample (random_start=False)
    // last-picked coords: point 0 (uniform scalar loads)
    float lx = p[0], ly = p[1], lz = p[2];

    for (int step = 1; step < S; ++step) {
        float bv = -1.0f;
        int   bi = 0;
#pragma unroll
        for (int j = 0; j < PPT; ++j) {
            // Exact f32 arithmetic, no FMA contraction: ((dx*dx + dy*dy) + dz*dz)
            float dx = __fsub_rn(px[j], lx);
            float dy = __fsub_rn(py[j], ly);
            float dz = __fsub_rn(pz[j], lz);
            float d  = __fadd_rn(__fadd_rn(__fmul_rn(dx, dx), __fmul_rn(dy, dy)),
                                 __fmul_rn(dz, dz));
            float nd = fminf(dd[j], d);
            dd[j] = nd;
            if (nd > bv) { bv = nd; bi = base + j; }   // strict > keeps lowest index
        }
        // pack (value, ~index): u64 max == argmax with lowest-index tie-break
        // (dd >= 0 so the IEEE bit pattern is order-preserving)
        unsigned long long key =
            ((unsigned long long)__float_as_uint(bv) << 32) | (unsigned int)(~bi);
#pragma unroll
        for (int off = 32; off >= 1; off >>= 1) {
            unsigned long long o = __shfl_down(key, off);
            if (o > key) key = o;
        }
        if (lane == 0) s_part[step & 1][wave] = key;
        __syncthreads();

        unsigned long long bk = s_part[step & 1][0];
#pragma unroll
        for (int q = 1; q < NWAVE; ++q) {
            unsigned long long o = s_part[step & 1][q];
            if (o > bk) bk = o;
        }
        int wi = (int)(~(unsigned int)bk);            // recover index
        if (t == 0) seq[b * S + step] = wi;
        // broadcast winner coords via scalar loads (no second barrier)
        int wis = __builtin_amdgcn_readfirstlane(wi);
        lx = p[wis * 3 + 0];
        ly = p[wis * 3 + 1];
        lz = p[wis * 3 + 2];
    }
}

// ---------------- Kernel 2: sort FPS indices (bitmap rank), gather dst ------
#define NT_SORT 512
__global__ __launch_bounds__(NT_SORT)
void sort_gather_kernel(const float* __restrict__ pts, const int* __restrict__ seq,
                        int* __restrict__ sorted, float* __restrict__ out) {
    const int b = blockIdx.x;
    const int t = threadIdx.x;
    __shared__ unsigned int bm[N / 32];   // 512 words
    __shared__ int pfx[N / 32];           // inclusive popcount prefix
    __shared__ int s_sorted[S];

    for (int i = t; i < N / 32; i += NT_SORT) bm[i] = 0u;
    __syncthreads();
    for (int i = t; i < S; i += NT_SORT) {
        int v = seq[b * S + i];
        atomicOr(&bm[v >> 5], 1u << (v & 31));
    }
    __syncthreads();

    // Hillis-Steele inclusive scan over 512 word popcounts (NT_SORT == 512)
    int myc = __popc(bm[t]);
    pfx[t] = myc;
    __syncthreads();
    for (int off = 1; off < N / 32; off <<= 1) {
        int v = (t >= off) ? pfx[t - off] : 0;
        __syncthreads();
        pfx[t] += v;
        __syncthreads();
    }

    for (int i = t; i < S; i += NT_SORT) {
        int v = seq[b * S + i];
        int w = v >> 5;
        int rank = pfx[w] - __popc(bm[w]) + __popc(bm[w] & ((1u << (v & 31)) - 1u));
        s_sorted[rank] = v;
    }
    __syncthreads();

    for (int r = t; r < S; r += NT_SORT) {
        int v = s_sorted[r];
        int g = b * S + r;
        sorted[g] = v;
        out[OFF_COORD + 3 * (size_t)g + 0] = pts[((size_t)b * N + v) * 3 + 0];
        out[OFF_COORD + 3 * (size_t)g + 1] = pts[((size_t)b * N + v) * 3 + 1];
        out[OFF_COORD + 3 * (size_t)g + 2] = pts[((size_t)b * N + v) * 3 + 2];
        out[OFF_BATCH + g] = (float)b;
        out[OFF_NIDX + g]  = (float)(v + b * N);
    }
}

// ---------------- Kernel 3: radius ball query, one wave per dst point -------
#define CAP 512                 // in-radius candidate cap (mean ~35, P(>512)~0)
__global__ __launch_bounds__(256)
void ballq_kernel(const float* __restrict__ pts, const int* __restrict__ sorted,
                  float* __restrict__ out) {
    const int w    = threadIdx.x >> 6;
    const int lane = threadIdx.x & 63;
    const int g    = blockIdx.x * 4 + w;     // dst id, 0..B*S-1
    const int b    = g >> 12;                // / S
    const float R2 = (float)(0.08 * 0.08);   // JAX weak-scalar f32 demotion

    __shared__ float cd2[4][CAP];
    __shared__ int   cidx[4][CAP];
    __shared__ int   coor[4][K];

    const float Dx = out[OFF_COORD + 3 * (size_t)g + 0];
    const float Dy = out[OFF_COORD + 3 * (size_t)g + 1];
    const float Dz = out[OFF_COORD + 3 * (size_t)g + 2];
    const int self = sorted[g];

    const float* p = pts + (size_t)b * N * 3;
    const unsigned long long ltmask = (lane == 63) ? 0x7fffffffffffffffull
                                                   : ((1ull << lane) - 1ull);
    int cnt = 0, oor = 0;
    for (int i0 = 0; i0 < N; i0 += 64) {
        int i = i0 + lane;
        float dx = __fsub_rn(Dx, p[i * 3 + 0]);
        float dy = __fsub_rn(Dy, p[i * 3 + 1]);
        float dz = __fsub_rn(Dz, p[i * 3 + 2]);
        float d2 = __fadd_rn(__fadd_rn(__fmul_rn(dx, dx), __fmul_rn(dy, dy)),
                             __fmul_rn(dz, dz));
        bool in = (d2 <= R2);
        unsigned long long m = __ballot(in);
        if (in) {
            int pos = cnt + __popcll(m & ltmask);
            if (pos < CAP) { cd2[w][pos] = d2; cidx[w][pos] = i; }
        }
        if (oor < K) {  // collect first K out-of-radius indices (ascending)
            unsigned long long m2 = ~m;
            if (!in) {
                int p2 = oor + __popcll(m2 & ltmask);
                if (p2 < K) coor[w][p2] = i;
            }
            oor += __popcll(m2);
            if (oor > K) oor = K;
        }
        cnt += __popcll(m);
    }

    const int M  = cnt < CAP ? cnt : CAP;
    const int Mk = M < K ? M : K;
    const size_t eb = (size_t)g * K;
    int deg = 0;
    for (int c = lane; c < M; c += 64) {
        float myd = cd2[w][c];
        int   myi = cidx[w][c];
        int rank = 0;
        for (int j = 0; j < M; ++j) {
            float dj = cd2[w][j];
            int   ij = cidx[w][j];
            rank += (dj < myd || (dj == myd && ij < myi)) ? 1 : 0;
        }
        if (rank < K) {
            bool valid = (myi != self);
            out[OFF_ESRC + eb + rank] = (float)(myi + b * N);
            out[OFF_MASK + eb + rank] = valid ? 1.0f : 0.0f;
            deg += valid ? 1 : 0;
        }
    }
    for (int r = lane; r < K; r += 64) {
        out[OFF_EDST + eb + r] = (float)g;        // b*S + s == g
        if (r >= Mk) {                            // top_k pad: lowest-index OOR pts
            out[OFF_ESRC + eb + r] = (float)(coor[w][r - Mk] + b * N);
            out[OFF_MASK + eb + r] = 0.0f;
        }
    }
#pragma unroll
    for (int off = 32; off >= 1; off >>= 1) deg += __shfl_down(deg, off);
    if (lane == 0) out[OFF_DEG + g] = (float)deg;
}

extern "C" void kernel_launch(void* const* d_in, const int* in_sizes, int n_in,
                              void* d_out, int out_size, void* d_ws, size_t ws_size,
                              hipStream_t stream) {
    const float* pts = (const float*)d_in[0];
    float* out = (float*)d_out;
    int* seq    = (int*)d_ws;
    int* sorted = seq + (size_t)B * S;

    fps_kernel<<<B, NT_FPS, 0, stream>>>(pts, seq);
    sort_gather_kernel<<<B, NT_SORT, 0, stream>>>(pts, seq, sorted, out);
    ballq_kernel<<<(B * S) / 4, 256, 0, stream>>>(pts, sorted, out);
}

// Round 3
// 5015.820 us; speedup vs baseline: 2.6874x; 1.4039x over previous
//
#include <hip/hip_runtime.h>
#include <hip/hip_bf16.h>

// Problem constants (match the reference)
constexpr int B = 4;
constexpr int N = 16384;
constexpr int S = 4096;       // N * 0.25
constexpr int K = 32;
constexpr float BIG = 1e30f;

// Output layout (flat f32, concatenated in reference return order)
constexpr size_t OFF_COORD = 0;                       // node_coord_dst [B*S*3]
constexpr size_t OFF_ESRC  = (size_t)B * S * 3;       // edge_src [B*S*K]
constexpr size_t OFF_EDST  = OFF_ESRC + (size_t)B * S * K;
constexpr size_t OFF_MASK  = OFF_EDST + (size_t)B * S * K;
constexpr size_t OFF_DEG   = OFF_MASK + (size_t)B * S * K;
constexpr size_t OFF_BATCH = OFF_DEG + (size_t)B * S;
constexpr size_t OFF_NIDX  = OFF_BATCH + (size_t)B * S;

// ============ Kernel 0: Morton counting-sort (one block per cloud) =========
// 14-bit code (x:5, y:5, z:4) -> 16384 cells, packed u16 counters in LDS.
// Output: sbuf[pos] = {x, y, z, bitcast(orig_idx)} in Morton order.
// Within-cell order is nondeterministic (atomics) but the FPS trajectory is
// chunk-independent (exact min + orig-idx tie-break), so outputs stay exact.
#define NT_MS 1024
__global__ __launch_bounds__(NT_MS)
void morton_sort_kernel(const float* __restrict__ pts, float4* __restrict__ sbuf) {
    const int b = blockIdx.x, t = threadIdx.x;
    const int lane = t & 63, wave = t >> 6;
    const float* p = pts + (size_t)b * N * 3;
    float4* sb = sbuf + (size_t)b * N;

    __shared__ unsigned int cnt[8192];   // 16384 u16 counters packed
    __shared__ int s_wsum[16];

    for (int i = t; i < 8192; i += NT_MS) cnt[i] = 0u;
    __syncthreads();

    float xx[16], yy[16], zz[16];
    int code[16];
#pragma unroll
    for (int j = 0; j < 16; ++j) {
        int i = t + j * NT_MS;
        float x = p[i * 3 + 0], y = p[i * 3 + 1], z = p[i * 3 + 2];
        xx[j] = x; yy[j] = y; zz[j] = z;
        int xi = min(31, (int)(x * 32.0f));
        int yi = min(31, (int)(y * 32.0f));
        int zi = min(15, (int)(z * 16.0f));
        int c = 0;
#pragma unroll
        for (int k = 0; k < 4; ++k) {
            c |= ((zi >> k) & 1) << (3 * k);
            c |= ((yi >> k) & 1) << (3 * k + 1);
            c |= ((xi >> k) & 1) << (3 * k + 2);
        }
        c |= ((xi >> 4) & 1) << 12;
        c |= ((yi >> 4) & 1) << 13;
        code[j] = c;
        atomicAdd(&cnt[c >> 1], (c & 1) ? 0x10000u : 1u);
    }
    __syncthreads();

    // exclusive prefix over 16384 cell counts; thread owns words [t*8, t*8+8)
    unsigned int w[8];
    int tot = 0;
#pragma unroll
    for (int k = 0; k < 8; ++k) {
        w[k] = cnt[t * 8 + k];
        tot += (int)(w[k] & 0xffffu) + (int)(w[k] >> 16);
    }
    int inc = tot;
#pragma unroll
    for (int off = 1; off < 64; off <<= 1) {
        int v = __shfl_up(inc, off);
        if (lane >= off) inc += v;
    }
    if (lane == 63) s_wsum[wave] = inc;
    __syncthreads();
    int wbase = 0;
#pragma unroll
    for (int q = 0; q < 16; ++q) {
        int v = s_wsum[q];
        if (q < wave) wbase += v;
    }
    int excl = wbase + inc - tot;
#pragma unroll
    for (int k = 0; k < 8; ++k) {
        unsigned int c0 = (unsigned int)excl;
        unsigned int c1 = c0 + (w[k] & 0xffffu);
        cnt[t * 8 + k] = c0 | (c1 << 16);
        excl = (int)(c1 + (w[k] >> 16));
    }
    __syncthreads();

    // scatter
#pragma unroll
    for (int j = 0; j < 16; ++j) {
        int i = t + j * NT_MS;
        int c = code[j];
        unsigned int old = atomicAdd(&cnt[c >> 1], (c & 1) ? 0x10000u : 1u);
        int pos = (c & 1) ? (int)(old >> 16) : (int)(old & 0xffffu);
        sb[pos] = make_float4(xx[j], yy[j], zz[j], __int_as_float(i));
    }
}

// ============ Kernel 1: pruned FPS (one block per cloud) ====================
// 1024 threads x 16-point Morton chunk each, all state pinned in VGPRs.
// Per step: bbox lower-bound test vs chunk max -> sparse exact updates ->
// u64 (value, ~orig_idx) block argmax -> winner coords via scalar load.
#define NT_FP 1024
#define CPT 16            // points per chunk/thread

__global__ __launch_bounds__(NT_FP, 4)
void fps_pruned_kernel(const float* __restrict__ pts, const float4* __restrict__ sbuf,
                       int* __restrict__ seq) {
    const int b = blockIdx.x, t = threadIdx.x;
    const int lane = t & 63, wave = t >> 6;
    const float* p = pts + (size_t)b * N * 3;
    const float4* sb = sbuf + (size_t)b * N;

    float px[CPT], py[CPT], pz[CPT], dd[CPT];
    unsigned int noi[CPT];             // ~orig_idx (tie-break key)
    float blx = BIG, bly = BIG, blz = BIG, bhx = -BIG, bhy = -BIG, bhz = -BIG;
#pragma unroll
    for (int j = 0; j < CPT; ++j) {
        float4 v = sb[t * CPT + j];
        px[j] = v.x; py[j] = v.y; pz[j] = v.z;
        noi[j] = ~(unsigned int)__float_as_int(v.w);
        dd[j] = BIG;
        blx = fminf(blx, v.x); bhx = fmaxf(bhx, v.x);
        bly = fminf(bly, v.y); bhy = fmaxf(bhy, v.y);
        blz = fminf(blz, v.z); bhz = fmaxf(bhz, v.z);
    }
    // pin state in VGPRs: values become opaque -> no rematerialization/reload
#pragma unroll
    for (int j = 0; j < CPT; ++j)
        asm volatile("" : "+v"(px[j]), "+v"(py[j]), "+v"(pz[j]), "+v"(noi[j]));
    asm volatile("" : "+v"(blx), "+v"(bly), "+v"(blz), "+v"(bhx), "+v"(bhy), "+v"(bhz));

    __shared__ unsigned long long sp[2][NT_FP / 64];   // parity double-buffer

    if (t == 0) seq[b * S + 0] = 0;        // first sample (random_start=False)
    float lx = p[0], ly = p[1], lz = p[2];
    unsigned long long bkey = ((unsigned long long)__float_as_uint(BIG) << 32);

    for (int step = 1; step < S; ++step) {
        // conservative bbox lower bound of d^2(chunk, c); margin covers rounding
        float tx = fmaxf(fmaxf(blx - lx, lx - bhx), 0.0f);
        float ty = fmaxf(fmaxf(bly - ly, ly - bhy), 0.0f);
        float tz = fmaxf(fmaxf(blz - lz, lz - bhz), 0.0f);
        float lb = tx * tx + ty * ty + tz * tz;
        float bmax = __uint_as_float((unsigned int)(bkey >> 32));
        if (lb * 0.999998f < bmax) {
            unsigned long long k = 0ull;
#pragma unroll
            for (int j = 0; j < CPT; ++j) {
                // Exact f32, no FMA contraction: ((dx*dx + dy*dy) + dz*dz)
                float dx = __fsub_rn(px[j], lx);
                float dy = __fsub_rn(py[j], ly);
                float dz = __fsub_rn(pz[j], lz);
                float d  = __fadd_rn(__fadd_rn(__fmul_rn(dx, dx), __fmul_rn(dy, dy)),
                                     __fmul_rn(dz, dz));
                float nd = fminf(dd[j], d);       // exact, order-independent
                dd[j] = nd;
                unsigned long long pk =
                    ((unsigned long long)__float_as_uint(nd) << 32) | noi[j];
                k = (pk > k) ? pk : k;            // equal value -> smaller orig idx
            }
            bkey = k;
        }
        // block argmax over 1024 chunk keys (rotate-reduce: all lanes get max)
        unsigned long long r = bkey;
#pragma unroll
        for (int off = 32; off >= 1; off >>= 1) {
            unsigned long long o = __shfl_down(r, off);
            r = (o > r) ? o : r;
        }
        if (lane == 0) sp[step & 1][wave] = r;
        __syncthreads();
        unsigned long long g = sp[step & 1][0];
#pragma unroll
        for (int q = 1; q < NT_FP / 64; ++q) {
            unsigned long long o = sp[step & 1][q];
            g = (o > g) ? o : g;
        }
        int wi = (int)(~(unsigned int)g);
        if (t == 0) seq[b * S + step] = wi;
        int wis = __builtin_amdgcn_readfirstlane(wi);
        lx = p[wis * 3 + 0];
        ly = p[wis * 3 + 1];
        lz = p[wis * 3 + 2];
    }
}

// ============ Fallback FPS (round-2 kernel, used only if ws too small) ======
#define NT_FPS 512
#define PPT (N / NT_FPS)
#define NWAVE (NT_FPS / 64)
__global__ __launch_bounds__(NT_FPS)
void fps_kernel(const float* __restrict__ pts, int* __restrict__ seq) {
    const int b = blockIdx.x;
    const float* p = pts + (size_t)b * N * 3;
    const int t = threadIdx.x;
    const int lane = t & 63;
    const int wave = t >> 6;
    float px[PPT], py[PPT], pz[PPT], dd[PPT];
    const int base = t * PPT;
#pragma unroll
    for (int j = 0; j < PPT; ++j) {
        px[j] = p[(base + j) * 3 + 0];
        py[j] = p[(base + j) * 3 + 1];
        pz[j] = p[(base + j) * 3 + 2];
        dd[j] = BIG;
    }
#pragma unroll
    for (int j = 0; j < PPT; ++j)
        asm volatile("" : "+v"(px[j]), "+v"(py[j]), "+v"(pz[j]));
    __shared__ unsigned long long s_part[2][NWAVE];
    if (t == 0) seq[b * S + 0] = 0;
    float lx = p[0], ly = p[1], lz = p[2];
    for (int step = 1; step < S; ++step) {
        float bv = -1.0f;
        int bi = 0;
#pragma unroll
        for (int j = 0; j < PPT; ++j) {
            float dx = __fsub_rn(px[j], lx);
            float dy = __fsub_rn(py[j], ly);
            float dz = __fsub_rn(pz[j], lz);
            float d  = __fadd_rn(__fadd_rn(__fmul_rn(dx, dx), __fmul_rn(dy, dy)),
                                 __fmul_rn(dz, dz));
            float nd = fminf(dd[j], d);
            dd[j] = nd;
            if (nd > bv) { bv = nd; bi = base + j; }
        }
        unsigned long long key =
            ((unsigned long long)__float_as_uint(bv) << 32) | (unsigned int)(~bi);
#pragma unroll
        for (int off = 32; off >= 1; off >>= 1) {
            unsigned long long o = __shfl_down(key, off);
            if (o > key) key = o;
        }
        if (lane == 0) s_part[step & 1][wave] = key;
        __syncthreads();
        unsigned long long bk = s_part[step & 1][0];
#pragma unroll
        for (int q = 1; q < NWAVE; ++q) {
            unsigned long long o = s_part[step & 1][q];
            if (o > bk) bk = o;
        }
        int wi = (int)(~(unsigned int)bk);
        if (t == 0) seq[b * S + step] = wi;
        int wis = __builtin_amdgcn_readfirstlane(wi);
        lx = p[wis * 3 + 0];
        ly = p[wis * 3 + 1];
        lz = p[wis * 3 + 2];
    }
}

// ============ Kernel 2: sort FPS indices (bitmap rank), gather dst ==========
#define NT_SORT 512
__global__ __launch_bounds__(NT_SORT)
void sort_gather_kernel(const float* __restrict__ pts, const int* __restrict__ seq,
                        int* __restrict__ sorted, float* __restrict__ out) {
    const int b = blockIdx.x;
    const int t = threadIdx.x;
    __shared__ unsigned int bm[N / 32];
    __shared__ int pfx[N / 32];
    __shared__ int s_sorted[S];

    for (int i = t; i < N / 32; i += NT_SORT) bm[i] = 0u;
    __syncthreads();
    for (int i = t; i < S; i += NT_SORT) {
        int v = seq[b * S + i];
        atomicOr(&bm[v >> 5], 1u << (v & 31));
    }
    __syncthreads();

    int myc = __popc(bm[t]);
    pfx[t] = myc;
    __syncthreads();
    for (int off = 1; off < N / 32; off <<= 1) {
        int v = (t >= off) ? pfx[t - off] : 0;
        __syncthreads();
        pfx[t] += v;
        __syncthreads();
    }

    for (int i = t; i < S; i += NT_SORT) {
        int v = seq[b * S + i];
        int w = v >> 5;
        int rank = pfx[w] - __popc(bm[w]) + __popc(bm[w] & ((1u << (v & 31)) - 1u));
        s_sorted[rank] = v;
    }
    __syncthreads();

    for (int r = t; r < S; r += NT_SORT) {
        int v = s_sorted[r];
        int g = b * S + r;
        sorted[g] = v;
        out[OFF_COORD + 3 * (size_t)g + 0] = pts[((size_t)b * N + v) * 3 + 0];
        out[OFF_COORD + 3 * (size_t)g + 1] = pts[((size_t)b * N + v) * 3 + 1];
        out[OFF_COORD + 3 * (size_t)g + 2] = pts[((size_t)b * N + v) * 3 + 2];
        out[OFF_BATCH + g] = (float)b;
        out[OFF_NIDX + g]  = (float)(v + b * N);
    }
}

// ============ Kernel 3: radius ball query, one wave per dst point ===========
#define CAP 512
__global__ __launch_bounds__(256)
void ballq_kernel(const float* __restrict__ pts, const int* __restrict__ sorted,
                  float* __restrict__ out) {
    const int w    = threadIdx.x >> 6;
    const int lane = threadIdx.x & 63;
    const int g    = blockIdx.x * 4 + w;
    const int b    = g >> 12;
    const float R2 = (float)(0.08 * 0.08);

    __shared__ float cd2[4][CAP];
    __shared__ int   cidx[4][CAP];
    __shared__ int   coor[4][K];

    const float Dx = out[OFF_COORD + 3 * (size_t)g + 0];
    const float Dy = out[OFF_COORD + 3 * (size_t)g + 1];
    const float Dz = out[OFF_COORD + 3 * (size_t)g + 2];
    const int self = sorted[g];

    const float* p = pts + (size_t)b * N * 3;
    const unsigned long long ltmask = (lane == 63) ? 0x7fffffffffffffffull
                                                   : ((1ull << lane) - 1ull);
    int cnt = 0, oor = 0;
    for (int i0 = 0; i0 < N; i0 += 64) {
        int i = i0 + lane;
        float dx = __fsub_rn(Dx, p[i * 3 + 0]);
        float dy = __fsub_rn(Dy, p[i * 3 + 1]);
        float dz = __fsub_rn(Dz, p[i * 3 + 2]);
        float d2 = __fadd_rn(__fadd_rn(__fmul_rn(dx, dx), __fmul_rn(dy, dy)),
                             __fmul_rn(dz, dz));
        bool in = (d2 <= R2);
        unsigned long long m = __ballot(in);
        if (in) {
            int pos = cnt + __popcll(m & ltmask);
            if (pos < CAP) { cd2[w][pos] = d2; cidx[w][pos] = i; }
        }
        if (oor < K) {
            unsigned long long m2 = ~m;
            if (!in) {
                int p2 = oor + __popcll(m2 & ltmask);
                if (p2 < K) coor[w][p2] = i;
            }
            oor += __popcll(m2);
            if (oor > K) oor = K;
        }
        cnt += __popcll(m);
    }

    const int M  = cnt < CAP ? cnt : CAP;
    const int Mk = M < K ? M : K;
    const size_t eb = (size_t)g * K;
    int deg = 0;
    for (int c = lane; c < M; c += 64) {
        float myd = cd2[w][c];
        int   myi = cidx[w][c];
        int rank = 0;
        for (int j = 0; j < M; ++j) {
            float dj = cd2[w][j];
            int   ij = cidx[w][j];
            rank += (dj < myd || (dj == myd && ij < myi)) ? 1 : 0;
        }
        if (rank < K) {
            bool valid = (myi != self);
            out[OFF_ESRC + eb + rank] = (float)(myi + b * N);
            out[OFF_MASK + eb + rank] = valid ? 1.0f : 0.0f;
            deg += valid ? 1 : 0;
        }
    }
    for (int r = lane; r < K; r += 64) {
        out[OFF_EDST + eb + r] = (float)g;
        if (r >= Mk) {
            out[OFF_ESRC + eb + r] = (float)(coor[w][r - Mk] + b * N);
            out[OFF_MASK + eb + r] = 0.0f;
        }
    }
#pragma unroll
    for (int off = 32; off >= 1; off >>= 1) deg += __shfl_down(deg, off);
    if (lane == 0) out[OFF_DEG + g] = (float)deg;
}

extern "C" void kernel_launch(void* const* d_in, const int* in_sizes, int n_in,
                              void* d_out, int out_size, void* d_ws, size_t ws_size,
                              hipStream_t stream) {
    const float* pts = (const float*)d_in[0];
    float* out = (float*)d_out;

    const size_t sbuf_bytes = (size_t)B * N * sizeof(float4);   // 1 MB
    const size_t need = sbuf_bytes + 2 * (size_t)B * S * sizeof(int);

    if (ws_size >= need) {
        float4* sbuf = (float4*)d_ws;
        int* seq    = (int*)((char*)d_ws + sbuf_bytes);
        int* sorted = seq + (size_t)B * S;
        morton_sort_kernel<<<B, NT_MS, 0, stream>>>(pts, sbuf);
        fps_pruned_kernel<<<B, NT_FP, 0, stream>>>(pts, sbuf, seq);
        sort_gather_kernel<<<B, NT_SORT, 0, stream>>>(pts, seq, sorted, out);
        ballq_kernel<<<(B * S) / 4, 256, 0, stream>>>(pts, sorted, out);
    } else {
        int* seq    = (int*)d_ws;
        int* sorted = seq + (size_t)B * S;
        fps_kernel<<<B, NT_FPS, 0, stream>>>(pts, seq);
        sort_gather_kernel<<<B, NT_SORT, 0, stream>>>(pts, seq, sorted, out);
        ballq_kernel<<<(B * S) / 4, 256, 0, stream>>>(pts, sorted, out);
    }
}

// Round 4
// 4979.830 us; speedup vs baseline: 2.7068x; 1.0072x over previous
//
#include <hip/hip_runtime.h>
#include <hip/hip_bf16.h>

// Problem constants (match the reference)
constexpr int B = 4;
constexpr int N = 16384;
constexpr int S = 4096;       // N * 0.25
constexpr int K = 32;
constexpr float BIG = 1e30f;

// Output layout (flat f32, concatenated in reference return order)
constexpr size_t OFF_COORD = 0;                       // node_coord_dst [B*S*3]
constexpr size_t OFF_ESRC  = (size_t)B * S * 3;       // edge_src [B*S*K]
constexpr size_t OFF_EDST  = OFF_ESRC + (size_t)B * S * K;
constexpr size_t OFF_MASK  = OFF_EDST + (size_t)B * S * K;
constexpr size_t OFF_DEG   = OFF_MASK + (size_t)B * S * K;
constexpr size_t OFF_BATCH = OFF_DEG + (size_t)B * S;
constexpr size_t OFF_NIDX  = OFF_BATCH + (size_t)B * S;

// ============ Kernel 0: Morton counting-sort (one block per cloud) =========
#define NT_MS 1024
__global__ __launch_bounds__(NT_MS)
void morton_sort_kernel(const float* __restrict__ pts, float4* __restrict__ sbuf) {
    const int b = blockIdx.x, t = threadIdx.x;
    const int lane = t & 63, wave = t >> 6;
    const float* p = pts + (size_t)b * N * 3;
    float4* sb = sbuf + (size_t)b * N;

    __shared__ unsigned int cnt[8192];   // 16384 u16 counters packed
    __shared__ int s_wsum[16];

    for (int i = t; i < 8192; i += NT_MS) cnt[i] = 0u;
    __syncthreads();

    float xx[16], yy[16], zz[16];
    int code[16];
#pragma unroll
    for (int j = 0; j < 16; ++j) {
        int i = t + j * NT_MS;
        float x = p[i * 3 + 0], y = p[i * 3 + 1], z = p[i * 3 + 2];
        xx[j] = x; yy[j] = y; zz[j] = z;
        int xi = min(31, (int)(x * 32.0f));
        int yi = min(31, (int)(y * 32.0f));
        int zi = min(15, (int)(z * 16.0f));
        int c = 0;
#pragma unroll
        for (int k = 0; k < 4; ++k) {
            c |= ((zi >> k) & 1) << (3 * k);
            c |= ((yi >> k) & 1) << (3 * k + 1);
            c |= ((xi >> k) & 1) << (3 * k + 2);
        }
        c |= ((xi >> 4) & 1) << 12;
        c |= ((yi >> 4) & 1) << 13;
        code[j] = c;
        atomicAdd(&cnt[c >> 1], (c & 1) ? 0x10000u : 1u);
    }
    __syncthreads();

    // exclusive prefix over 16384 cell counts; thread owns words [t*8, t*8+8)
    unsigned int w[8];
    int tot = 0;
#pragma unroll
    for (int k = 0; k < 8; ++k) {
        w[k] = cnt[t * 8 + k];
        tot += (int)(w[k] & 0xffffu) + (int)(w[k] >> 16);
    }
    int inc = tot;
#pragma unroll
    for (int off = 1; off < 64; off <<= 1) {
        int v = __shfl_up(inc, off);
        if (lane >= off) inc += v;
    }
    if (lane == 63) s_wsum[wave] = inc;
    __syncthreads();
    int wbase = 0;
#pragma unroll
    for (int q = 0; q < 16; ++q) {
        int v = s_wsum[q];
        if (q < wave) wbase += v;
    }
    int excl = wbase + inc - tot;
#pragma unroll
    for (int k = 0; k < 8; ++k) {
        unsigned int c0 = (unsigned int)excl;
        unsigned int c1 = c0 + (w[k] & 0xffffu);
        cnt[t * 8 + k] = c0 | (c1 << 16);
        excl = (int)(c1 + (w[k] >> 16));
    }
    __syncthreads();

    // scatter
#pragma unroll
    for (int j = 0; j < 16; ++j) {
        int i = t + j * NT_MS;
        int c = code[j];
        unsigned int old = atomicAdd(&cnt[c >> 1], (c & 1) ? 0x10000u : 1u);
        int pos = (c & 1) ? (int)(old >> 16) : (int)(old & 0xffffu);
        sb[pos] = make_float4(xx[j], yy[j], zz[j], __int_as_float(i));
    }
}

// ============ Kernel 1: pruned FPS (one block per cloud) ====================
// 1024 threads x 16-point Morton chunk each, all state held in VGPRs.
// amdgpu_waves_per_eu(4,4): clamp occupancy target to exactly 4 waves/SIMD
// (= the 1 resident block) so the allocator gets the full 128-VGPR budget and
// stops spilling to scratch to chase 8 waves/SIMD.
#define NT_FP 1024
#define CPT 16            // points per chunk/thread

__global__ __attribute__((amdgpu_flat_work_group_size(NT_FP, NT_FP)))
__attribute__((amdgpu_waves_per_eu(4, 4)))
void fps_pruned_kernel(const float* __restrict__ pts, const float4* __restrict__ sbuf,
                       int* __restrict__ seq) {
    const int b = blockIdx.x, t = threadIdx.x;
    const int lane = t & 63, wave = t >> 6;
    const float* p = pts + (size_t)b * N * 3;
    const float4* sb = sbuf + (size_t)b * N;

    float px[CPT], py[CPT], pz[CPT], dd[CPT];
    unsigned int noi[CPT];             // ~orig_idx (tie-break key)
    float blx = BIG, bly = BIG, blz = BIG, bhx = -BIG, bhy = -BIG, bhz = -BIG;
#pragma unroll
    for (int j = 0; j < CPT; ++j) {
        float4 v = sb[t * CPT + j];
        px[j] = v.x; py[j] = v.y; pz[j] = v.z;
        noi[j] = ~(unsigned int)__float_as_int(v.w);
        dd[j] = BIG;
        blx = fminf(blx, v.x); bhx = fmaxf(bhx, v.x);
        bly = fminf(bly, v.y); bhy = fmaxf(bhy, v.y);
        blz = fminf(blz, v.z); bhz = fmaxf(bhz, v.z);
    }
    // pin state in VGPRs: values become opaque -> cannot be rematerialized
#pragma unroll
    for (int j = 0; j < CPT; ++j)
        asm volatile("" : "+v"(px[j]), "+v"(py[j]), "+v"(pz[j]), "+v"(noi[j]));
    asm volatile("" : "+v"(blx), "+v"(bly), "+v"(blz), "+v"(bhx), "+v"(bhy), "+v"(bhz));

    __shared__ unsigned long long sp[2][NT_FP / 64];   // parity double-buffer

    if (t == 0) seq[b * S + 0] = 0;        // first sample (random_start=False)
    float lx = p[0], ly = p[1], lz = p[2];
    unsigned long long bkey = ((unsigned long long)__float_as_uint(BIG) << 32);

    for (int step = 1; step < S; ++step) {
        // conservative bbox lower bound of d^2(chunk, c); margin covers rounding
        float tx = fmaxf(fmaxf(blx - lx, lx - bhx), 0.0f);
        float ty = fmaxf(fmaxf(bly - ly, ly - bhy), 0.0f);
        float tz = fmaxf(fmaxf(blz - lz, lz - bhz), 0.0f);
        float lb = tx * tx + ty * ty + tz * tz;
        float bmax = __uint_as_float((unsigned int)(bkey >> 32));
        if (lb * 0.999998f < bmax) {
            unsigned long long k = 0ull;
#pragma unroll
            for (int j = 0; j < CPT; ++j) {
                // Exact f32, no FMA contraction: ((dx*dx + dy*dy) + dz*dz)
                float dx = __fsub_rn(px[j], lx);
                float dy = __fsub_rn(py[j], ly);
                float dz = __fsub_rn(pz[j], lz);
                float d  = __fadd_rn(__fadd_rn(__fmul_rn(dx, dx), __fmul_rn(dy, dy)),
                                     __fmul_rn(dz, dz));
                float nd = fminf(dd[j], d);       // exact, order-independent
                dd[j] = nd;
                unsigned long long pk =
                    ((unsigned long long)__float_as_uint(nd) << 32) | noi[j];
                k = (pk > k) ? pk : k;            // equal value -> smaller orig idx
            }
            bkey = k;
        }
        // block argmax over 1024 chunk keys
        unsigned long long r = bkey;
#pragma unroll
        for (int off = 32; off >= 1; off >>= 1) {
            unsigned long long o = __shfl_down(r, off);
            r = (o > r) ? o : r;
        }
        if (lane == 0) sp[step & 1][wave] = r;
        __syncthreads();
        unsigned long long g = sp[step & 1][0];
#pragma unroll
        for (int q = 1; q < NT_FP / 64; ++q) {
            unsigned long long o = sp[step & 1][q];
            g = (o > g) ? o : g;
        }
        int wi = (int)(~(unsigned int)g);
        if (t == 0) seq[b * S + step] = wi;
        int wis = __builtin_amdgcn_readfirstlane(wi);
        lx = p[wis * 3 + 0];
        ly = p[wis * 3 + 1];
        lz = p[wis * 3 + 2];
    }
}

// ============ Fallback FPS (used only if ws too small) ======================
#define NT_FPS 512
#define PPT (N / NT_FPS)
#define NWAVE (NT_FPS / 64)
__global__ __launch_bounds__(NT_FPS)
void fps_kernel(const float* __restrict__ pts, int* __restrict__ seq) {
    const int b = blockIdx.x;
    const float* p = pts + (size_t)b * N * 3;
    const int t = threadIdx.x;
    const int lane = t & 63;
    const int wave = t >> 6;
    float px[PPT], py[PPT], pz[PPT], dd[PPT];
    const int base = t * PPT;
#pragma unroll
    for (int j = 0; j < PPT; ++j) {
        px[j] = p[(base + j) * 3 + 0];
        py[j] = p[(base + j) * 3 + 1];
        pz[j] = p[(base + j) * 3 + 2];
        dd[j] = BIG;
    }
#pragma unroll
    for (int j = 0; j < PPT; ++j)
        asm volatile("" : "+v"(px[j]), "+v"(py[j]), "+v"(pz[j]));
    __shared__ unsigned long long s_part[2][NWAVE];
    if (t == 0) seq[b * S + 0] = 0;
    float lx = p[0], ly = p[1], lz = p[2];
    for (int step = 1; step < S; ++step) {
        float bv = -1.0f;
        int bi = 0;
#pragma unroll
        for (int j = 0; j < PPT; ++j) {
            float dx = __fsub_rn(px[j], lx);
            float dy = __fsub_rn(py[j], ly);
            float dz = __fsub_rn(pz[j], lz);
            float d  = __fadd_rn(__fadd_rn(__fmul_rn(dx, dx), __fmul_rn(dy, dy)),
                                 __fmul_rn(dz, dz));
            float nd = fminf(dd[j], d);
            dd[j] = nd;
            if (nd > bv) { bv = nd; bi = base + j; }
        }
        unsigned long long key =
            ((unsigned long long)__float_as_uint(bv) << 32) | (unsigned int)(~bi);
#pragma unroll
        for (int off = 32; off >= 1; off >>= 1) {
            unsigned long long o = __shfl_down(key, off);
            if (o > key) key = o;
        }
        if (lane == 0) s_part[step & 1][wave] = key;
        __syncthreads();
        unsigned long long bk = s_part[step & 1][0];
#pragma unroll
        for (int q = 1; q < NWAVE; ++q) {
            unsigned long long o = s_part[step & 1][q];
            if (o > bk) bk = o;
        }
        int wi = (int)(~(unsigned int)bk);
        if (t == 0) seq[b * S + step] = wi;
        int wis = __builtin_amdgcn_readfirstlane(wi);
        lx = p[wis * 3 + 0];
        ly = p[wis * 3 + 1];
        lz = p[wis * 3 + 2];
    }
}

// ============ Kernel 2: sort FPS indices (bitmap rank), gather dst ==========
#define NT_SORT 512
__global__ __launch_bounds__(NT_SORT)
void sort_gather_kernel(const float* __restrict__ pts, const int* __restrict__ seq,
                        int* __restrict__ sorted, float* __restrict__ out) {
    const int b = blockIdx.x;
    const int t = threadIdx.x;
    __shared__ unsigned int bm[N / 32];
    __shared__ int pfx[N / 32];
    __shared__ int s_sorted[S];

    for (int i = t; i < N / 32; i += NT_SORT) bm[i] = 0u;
    __syncthreads();
    for (int i = t; i < S; i += NT_SORT) {
        int v = seq[b * S + i];
        atomicOr(&bm[v >> 5], 1u << (v & 31));
    }
    __syncthreads();

    int myc = __popc(bm[t]);
    pfx[t] = myc;
    __syncthreads();
    for (int off = 1; off < N / 32; off <<= 1) {
        int v = (t >= off) ? pfx[t - off] : 0;
        __syncthreads();
        pfx[t] += v;
        __syncthreads();
    }

    for (int i = t; i < S; i += NT_SORT) {
        int v = seq[b * S + i];
        int w = v >> 5;
        int rank = pfx[w] - __popc(bm[w]) + __popc(bm[w] & ((1u << (v & 31)) - 1u));
        s_sorted[rank] = v;
    }
    __syncthreads();

    for (int r = t; r < S; r += NT_SORT) {
        int v = s_sorted[r];
        int g = b * S + r;
        sorted[g] = v;
        out[OFF_COORD + 3 * (size_t)g + 0] = pts[((size_t)b * N + v) * 3 + 0];
        out[OFF_COORD + 3 * (size_t)g + 1] = pts[((size_t)b * N + v) * 3 + 1];
        out[OFF_COORD + 3 * (size_t)g + 2] = pts[((size_t)b * N + v) * 3 + 2];
        out[OFF_BATCH + g] = (float)b;
        out[OFF_NIDX + g]  = (float)(v + b * N);
    }
}

// ============ Kernel 3: radius ball query, one wave per dst point ===========
#define CAP 512
__global__ __launch_bounds__(256)
void ballq_kernel(const float* __restrict__ pts, const int* __restrict__ sorted,
                  float* __restrict__ out) {
    const int w    = threadIdx.x >> 6;
    const int lane = threadIdx.x & 63;
    const int g    = blockIdx.x * 4 + w;
    const int b    = g >> 12;
    const float R2 = (float)(0.08 * 0.08);

    __shared__ float cd2[4][CAP];
    __shared__ int   cidx[4][CAP];
    __shared__ int   coor[4][K];

    const float Dx = out[OFF_COORD + 3 * (size_t)g + 0];
    const float Dy = out[OFF_COORD + 3 * (size_t)g + 1];
    const float Dz = out[OFF_COORD + 3 * (size_t)g + 2];
    const int self = sorted[g];

    const float* p = pts + (size_t)b * N * 3;
    const unsigned long long ltmask = (lane == 63) ? 0x7fffffffffffffffull
                                                   : ((1ull << lane) - 1ull);
    int cnt = 0, oor = 0;
    for (int i0 = 0; i0 < N; i0 += 64) {
        int i = i0 + lane;
        float dx = __fsub_rn(Dx, p[i * 3 + 0]);
        float dy = __fsub_rn(Dy, p[i * 3 + 1]);
        float dz = __fsub_rn(Dz, p[i * 3 + 2]);
        float d2 = __fadd_rn(__fadd_rn(__fmul_rn(dx, dx), __fmul_rn(dy, dy)),
                             __fmul_rn(dz, dz));
        bool in = (d2 <= R2);
        unsigned long long m = __ballot(in);
        if (in) {
            int pos = cnt + __popcll(m & ltmask);
            if (pos < CAP) { cd2[w][pos] = d2; cidx[w][pos] = i; }
        }
        if (oor < K) {
            unsigned long long m2 = ~m;
            if (!in) {
                int p2 = oor + __popcll(m2 & ltmask);
                if (p2 < K) coor[w][p2] = i;
            }
            oor += __popcll(m2);
            if (oor > K) oor = K;
        }
        cnt += __popcll(m);
    }

    const int M  = cnt < CAP ? cnt : CAP;
    const int Mk = M < K ? M : K;
    const size_t eb = (size_t)g * K;
    int deg = 0;
    for (int c = lane; c < M; c += 64) {
        float myd = cd2[w][c];
        int   myi = cidx[w][c];
        int rank = 0;
        for (int j = 0; j < M; ++j) {
            float dj = cd2[w][j];
            int   ij = cidx[w][j];
            rank += (dj < myd || (dj == myd && ij < myi)) ? 1 : 0;
        }
        if (rank < K) {
            bool valid = (myi != self);
            out[OFF_ESRC + eb + rank] = (float)(myi + b * N);
            out[OFF_MASK + eb + rank] = valid ? 1.0f : 0.0f;
            deg += valid ? 1 : 0;
        }
    }
    for (int r = lane; r < K; r += 64) {
        out[OFF_EDST + eb + r] = (float)g;
        if (r >= Mk) {
            out[OFF_ESRC + eb + r] = (float)(coor[w][r - Mk] + b * N);
            out[OFF_MASK + eb + r] = 0.0f;
        }
    }
#pragma unroll
    for (int off = 32; off >= 1; off >>= 1) deg += __shfl_down(deg, off);
    if (lane == 0) out[OFF_DEG + g] = (float)deg;
}

extern "C" void kernel_launch(void* const* d_in, const int* in_sizes, int n_in,
                              void* d_out, int out_size, void* d_ws, size_t ws_size,
                              hipStream_t stream) {
    const float* pts = (const float*)d_in[0];
    float* out = (float*)d_out;

    const size_t sbuf_bytes = (size_t)B * N * sizeof(float4);   // 1 MB
    const size_t need = sbuf_bytes + 2 * (size_t)B * S * sizeof(int);

    if (ws_size >= need) {
        float4* sbuf = (float4*)d_ws;
        int* seq    = (int*)((char*)d_ws + sbuf_bytes);
        int* sorted = seq + (size_t)B * S;
        morton_sort_kernel<<<B, NT_MS, 0, stream>>>(pts, sbuf);
        fps_pruned_kernel<<<B, NT_FP, 0, stream>>>(pts, sbuf, seq);
        sort_gather_kernel<<<B, NT_SORT, 0, stream>>>(pts, seq, sorted, out);
        ballq_kernel<<<(B * S) / 4, 256, 0, stream>>>(pts, sorted, out);
    } else {
        int* seq    = (int*)d_ws;
        int* sorted = seq + (size_t)B * S;
        fps_kernel<<<B, NT_FPS, 0, stream>>>(pts, seq);
        sort_gather_kernel<<<B, NT_SORT, 0, stream>>>(pts, seq, sorted, out);
        ballq_kernel<<<(B * S) / 4, 256, 0, stream>>>(pts, sorted, out);
    }
}